// Round 7
// baseline (221.102 us; speedup 1.0000x reference)
//
#include <hip/hip_runtime.h>
#include <hip/hip_bf16.h>
#include <math.h>

#define NUM_HEADS 16
#define D_KV 64
#define D_MODEL 1024
#define SEQ 2048
#define BATCH 2
#define LOG2E 1.4426950408889634f

using bf16x8 = __attribute__((ext_vector_type(8))) short;
using bf16x4 = __attribute__((ext_vector_type(4))) short;
using f32x4  = __attribute__((ext_vector_type(4))) float;

__device__ inline unsigned short f2bf(float f) {
  union { float f; unsigned int i; } v; v.f = f;
  unsigned int u = v.i;
  return (unsigned short)((u + 0x7FFFu + ((u >> 16) & 1u)) >> 16);
}
__device__ inline unsigned short f2bf_fast(float f) {
  union { float f; unsigned int i; } v; v.f = f;
  return (unsigned short)((v.i + 0x8000u) >> 16);
}

#if __has_builtin(__builtin_amdgcn_exp2f)
#define EXP2(x) __builtin_amdgcn_exp2f(x)
#else
#define EXP2(x) __expf((x) * 0.6931471805599453f)
#endif

__device__ inline unsigned int pk_bf16(float a, float b) {
#if __has_builtin(__builtin_amdgcn_cvt_pk_bf16_f32)
  auto v = __builtin_amdgcn_cvt_pk_bf16_f32(a, b);
  unsigned int u; __builtin_memcpy(&u, &v, 4);
  return u;
#else
  return ((unsigned int)f2bf_fast(b) << 16) | f2bf_fast(a);
#endif
}

// async global->LDS, 16 B per lane (dest lane-contiguous)
__device__ inline void gld_lds16(const unsigned short* g, unsigned short* l) {
  __builtin_amdgcn_global_load_lds(
      (const __attribute__((address_space(1))) unsigned int*)g,
      (__attribute__((address_space(3))) unsigned int*)l, 16, 0, 0);
}

// ---------------- fused prep: X convert + 4 weight transposes + bias table ----------------
__global__ __launch_bounds__(256) void prep_kernel(const float* __restrict__ X,
                                                   const float* __restrict__ W0,
                                                   const float* __restrict__ W1,
                                                   const float* __restrict__ W2,
                                                   const float* __restrict__ W3,
                                                   const float* __restrict__ tbl,
                                                   unsigned short* __restrict__ xbf,
                                                   unsigned short* __restrict__ wt,
                                                   float* __restrict__ biasF) {
  __shared__ __align__(16) unsigned short T[64][72];
  int bid = blockIdx.x;
  int t = threadIdx.x;
  if (bid < 2048) {
    int i = (bid * 256 + t) * 8;
    __align__(16) unsigned short tmp[8];
#pragma unroll
    for (int e = 0; e < 8; e++) tmp[e] = f2bf(X[i + e]);
    *(uint4*)&xbf[i] = *(uint4*)tmp;
  } else if (bid < 3072) {
    int rem = bid - 2048;
    int z = rem >> 8, tid = rem & 255;
    const float* in = (z == 0) ? W0 : (z == 1) ? W1 : (z == 2) ? W2 : W3;
    unsigned short* o = wt + (long)z * 1048576;
    int r0 = (tid & 15) * 64, c0 = (tid >> 4) * 64;
#pragma unroll
    for (int i = 0; i < 2; i++) {
      int c = t + 256 * i; int r = c >> 3, k8 = (c & 7) * 8;
      const float* src = &in[(long)(r0 + r) * 1024 + c0 + k8];
      __align__(16) unsigned short tmp[8];
#pragma unroll
      for (int e = 0; e < 8; e++) tmp[e] = f2bf(src[e]);
      *(uint4*)&T[r][k8] = *(uint4*)tmp;
    }
    __syncthreads();
#pragma unroll
    for (int i = 0; i < 2; i++) {
      int c = t + 256 * i; int r = c >> 3, k8 = (c & 7) * 8;
      __align__(16) unsigned short tmp[8];
#pragma unroll
      for (int e = 0; e < 8; e++) tmp[e] = T[k8 + e][r];
      *(uint4*)&o[(long)(c0 + r) * 1024 + r0 + k8] = *(uint4*)tmp;
    }
  } else {
#pragma unroll
    for (int ii = 0; ii < 16; ii++) {
      int idx = t + 256 * ii;
      if (idx >= 4095) break;
      int rel = idx - 2047;
      int bucket = (rel > 0) ? 16 : 0;
      int rp = rel < 0 ? -rel : rel;
      int add;
      if (rp < 8) add = rp;
      else {
        int rl = 8 + (int)(logf((float)rp * 0.125f) / logf(16.0f) * 8.0f);
        add = rl < 15 ? rl : 15;
      }
      bucket += add;
#pragma unroll
      for (int h = 0; h < 16; h++) biasF[h * 4096 + idx] = tbl[bucket * 16 + h] * LOG2E;
    }
  }
}

// ---------------- GEMM: C(MxN) = X(MxK) @ Wt(NxK)^T, K=1024 ----------------
// mode 0: z=0 (Q, log2e-scaled) / z=1 (K): bf16 (B,H,S,D); z=2 (V): bf16 TRANSPOSED (B,H,D,S).
// mode 1: fp32 row-major.
// All epilogues stage the C-tile in LDS (reusing the staging buffer) and emit
// coalesced 16B global stores — scattered short stores were the R6 bottleneck theory.
__global__ __launch_bounds__(256) void gemm_kernel(const unsigned short* __restrict__ X,
                                                   const unsigned short* __restrict__ Wt,
                                                   unsigned short* __restrict__ out_b,
                                                   unsigned short* __restrict__ out_vt,
                                                   float* __restrict__ out_f, int mode) {
  __shared__ __align__(16) unsigned short SMEM[128 * 136];   // loop: As|Bs; epilogue: C-tile
  unsigned short* As = SMEM;
  unsigned short* Bs = SMEM + 128 * 32;
  const int K = 1024;
  int m0 = blockIdx.x * 128;
  int n0 = blockIdx.y * 128;
  const unsigned short* W = Wt + (long)blockIdx.z * 1048576;
  unsigned short* outq = (mode == 0) ? out_b + (long)blockIdx.z * 4194304 : nullptr;
  float scale = (mode == 0 && blockIdx.z == 0) ? LOG2E : 1.0f;
  int t = threadIdx.x;
  int w = t >> 6, l = t & 63;
  int wr = (w >> 1) * 64, wc = (w & 1) * 64;
  int lr = l & 15, lq = l >> 4;
  f32x4 acc[4][4];
#pragma unroll
  for (int i = 0; i < 4; i++)
#pragma unroll
    for (int j = 0; j < 4; j++) acc[i][j] = (f32x4){0.f, 0.f, 0.f, 0.f};

  for (int k0 = 0; k0 < K; k0 += 32) {
#pragma unroll
    for (int i = 0; i < 2; i++) {
      int c = t + 256 * i;
      int r = c >> 2, kc = (c & 3) * 8;
      gld_lds16(&X[(long)(m0 + r) * K + k0 + kc], &As[c * 8]);
      gld_lds16(&W[(long)(n0 + r) * K + k0 + kc], &Bs[c * 8]);
    }
    __syncthreads();
    bf16x8 a[4], b[4];
#pragma unroll
    for (int mi = 0; mi < 4; mi++) a[mi] = *(const bf16x8*)&As[(wr + mi * 16 + lr) * 32 + lq * 8];
#pragma unroll
    for (int ni = 0; ni < 4; ni++) b[ni] = *(const bf16x8*)&Bs[(wc + ni * 16 + lr) * 32 + lq * 8];
#pragma unroll
    for (int mi = 0; mi < 4; mi++)
#pragma unroll
      for (int ni = 0; ni < 4; ni++)
        acc[mi][ni] = __builtin_amdgcn_mfma_f32_16x16x32_bf16(a[mi], b[ni], acc[mi][ni], 0, 0, 0);
    __syncthreads();   // also protects SMEM reuse by the epilogue
  }

  if (mode == 1) {
    // fp32 out, two 64-row passes through LDS (64 x 132 fp32 = 33.8 KB)
    float* Csf = (float*)SMEM;
#pragma unroll
    for (int p = 0; p < 2; p++) {
      if ((w >> 1) == p) {
#pragma unroll
        for (int mi = 0; mi < 4; mi++)
#pragma unroll
          for (int ni = 0; ni < 4; ni++)
#pragma unroll
            for (int r = 0; r < 4; r++)
              Csf[(mi * 16 + lq * 4 + r) * 132 + wc + ni * 16 + lr] = acc[mi][ni][r];
      }
      __syncthreads();
#pragma unroll
      for (int i = 0; i < 8; i++) {
        int c = t + 256 * i;
        int row = c >> 5, ch = c & 31;
        float4 v = *(const float4*)&Csf[row * 132 + ch * 4];
        *(float4*)&out_f[(long)(m0 + p * 64 + row) * 1024 + n0 + ch * 4] = v;
      }
      __syncthreads();
    }
  } else if (blockIdx.z == 2) {
    // V^T (B,H,D,S): stage transposed [n][m] (uint2 LDS writes), coalesced uint4 along s
    unsigned short* Cs = SMEM;
#pragma unroll
    for (int mi = 0; mi < 4; mi++)
#pragma unroll
      for (int ni = 0; ni < 4; ni++) {
        int nl = wc + ni * 16 + lr;
        int ml = wr + mi * 16 + lq * 4;
        unsigned int s0 = ((unsigned int)f2bf(acc[mi][ni][1]) << 16) | f2bf(acc[mi][ni][0]);
        unsigned int s1 = ((unsigned int)f2bf(acc[mi][ni][3]) << 16) | f2bf(acc[mi][ni][2]);
        *(uint2*)&Cs[nl * 136 + ml] = (uint2){s0, s1};
      }
    __syncthreads();
    int b2 = m0 >> 11, sbase = m0 & 2047;
#pragma unroll
    for (int i = 0; i < 8; i++) {
      int c = t + 256 * i;
      int row = c >> 4, ch = c & 15;       // row = n_local, ch*8 = s-offset
      uint4 v = *(const uint4*)&Cs[row * 136 + ch * 8];
      int n = n0 + row, h = n >> 6, d = n & 63;
      *(uint4*)&out_vt[(((long)(b2 * 16 + h) * 64 + d) << 11) + sbase + ch * 8] = v;
    }
  } else {
    // Q/K (B,H,S,D): stage [m][n], coalesced uint4 along d
    unsigned short* Cs = SMEM;
#pragma unroll
    for (int mi = 0; mi < 4; mi++)
#pragma unroll
      for (int ni = 0; ni < 4; ni++)
#pragma unroll
        for (int r = 0; r < 4; r++)
          Cs[(wr + mi * 16 + lq * 4 + r) * 136 + wc + ni * 16 + lr] = f2bf(acc[mi][ni][r] * scale);
    __syncthreads();
    int b2 = m0 >> 11, sbase = m0 & 2047;
#pragma unroll
    for (int i = 0; i < 8; i++) {
      int c = t + 256 * i;
      int row = c >> 4, ch = c & 15;       // row = m_local, ch*8 = n-offset
      uint4 v = *(const uint4*)&Cs[row * 136 + ch * 8];
      int n = n0 + ch * 8, h = n >> 6, d = n & 63;
      *(uint4*)&outq[((long)(b2 * 16 + h) * 2048 + sbase + row) * 64 + d] = v;
    }
  }
}

// ---------------- flash attention: 512-thread blocks, intra-block K-split (unchanged R6) ----------------
__global__ __launch_bounds__(512) void attn_kernel(const unsigned short* __restrict__ Q,
                                                   const unsigned short* __restrict__ Km,
                                                   const unsigned short* __restrict__ Vt,
                                                   const float* __restrict__ biasF,
                                                   unsigned short* __restrict__ O) {
  __shared__ __align__(16) unsigned short KV[4][4608];  // [0,1]=K par0/1, [2,3]=V par0/1 (64x72)
  __shared__ float biasS[2176];
  int q0 = blockIdx.x * 128;
  int bh = blockIdx.y;
  int b_ = bh >> 4, h = bh & 15;
  const unsigned short* Qb = Q  + (long)bh * SEQ * 64;
  const unsigned short* Kb = Km + (long)bh * SEQ * 64;
  const unsigned short* Vb = Vt + (long)bh * 64 * SEQ;
  const float* btabF = biasF + h * 4096;
  int t = threadIdx.x;
  int w = t >> 6, l = t & 63;
  int g = w >> 2, wg = w & 3;
  int lr = l & 15, lq = l >> 4;
  int qw = wg * 32;

  int gbase = 1920 - q0;
  for (int i = t; i < 2176; i += 512) {
    int gi = gbase + i; if (gi > 4094) gi = 4094;
    biasS[i] = btabF[gi];
  }

  bf16x8 aq[2][2];
#pragma unroll
  for (int qt = 0; qt < 2; qt++)
#pragma unroll
    for (int ks = 0; ks < 2; ks++)
      aq[qt][ks] = *(const bf16x8*)&Qb[(long)(q0 + qw + qt * 16 + lr) * 64 + ks * 32 + lq * 8];

  int rs = t >> 3, fs = (t & 7) * 8;

  uint4 kpa = *(const uint4*)&Kb[(long)rs * 64 + fs];
  uint4 kpb = *(const uint4*)&Kb[(long)(64 + rs) * 64 + fs];
  uint4 vpa = *(const uint4*)&Vb[(long)rs * SEQ + fs];
  uint4 vpb = *(const uint4*)&Vb[(long)rs * SEQ + 64 + fs];
  *(uint4*)&KV[0][rs * 72 + fs] = kpa;
  *(uint4*)&KV[1][rs * 72 + fs] = kpb;
  *(uint4*)&KV[2][rs * 72 + fs] = vpa;
  *(uint4*)&KV[3][rs * 72 + fs] = vpb;

  f32x4 accO[4][2];
  f32x4 accL[2];
#pragma unroll
  for (int qt = 0; qt < 2; qt++) {
    accL[qt] = (f32x4){0.f, 0.f, 0.f, 0.f};
#pragma unroll
    for (int dt = 0; dt < 4; dt++) accO[dt][qt] = (f32x4){0.f, 0.f, 0.f, 0.f};
  }

  bf16x4 ones4;
#pragma unroll
  for (int e = 0; e < 4; e++) ones4[e] = (short)0x3F80;

  int vb = 127 + lq * 4 - qw - lr;
  int pbc = vb - 16;

  for (int i = 0; i < 16; i++) {
    __syncthreads();
    int k0 = (2 * i + g) * 64;
    bool more = i < 15;

    float bbl[5][4];
    int pb = pbc + k0;
#pragma unroll
    for (int m = 0; m < 5; m++)
#pragma unroll
      for (int j = 0; j < 4; j++) bbl[m][j] = biasS[pb + 16 * m + j];

    bf16x8 bk[4][2];
#pragma unroll
    for (int kt = 0; kt < 4; kt++)
#pragma unroll
      for (int ks = 0; ks < 2; ks++)
        bk[kt][ks] = *(const bf16x8*)&KV[g][(kt * 16 + lr) * 72 + ks * 32 + lq * 8];

    if (more) {
      const unsigned short* Kn = Kb + (long)(2 * i + 2) * 64 * 64;
      const unsigned short* Vn = Vb + (2 * i + 2) * 64;
      kpa = *(const uint4*)&Kn[(long)rs * 64 + fs];
      kpb = *(const uint4*)&Kn[(long)(64 + rs) * 64 + fs];
      vpa = *(const uint4*)&Vn[(long)rs * SEQ + fs];
      vpb = *(const uint4*)&Vn[(long)rs * SEQ + 64 + fs];
    }

    f32x4 sacc[4][2];
#pragma unroll
    for (int kt = 0; kt < 4; kt++)
#pragma unroll
      for (int qt = 0; qt < 2; qt++) sacc[kt][qt] = (f32x4){0.f, 0.f, 0.f, 0.f};
#pragma unroll
    for (int ks = 0; ks < 2; ks++)
#pragma unroll
      for (int kt = 0; kt < 4; kt++)
#pragma unroll
        for (int qt = 0; qt < 2; qt++)
          sacc[kt][qt] = __builtin_amdgcn_mfma_f32_16x16x32_bf16(bk[kt][ks], aq[qt][ks], sacc[kt][qt], 0, 0, 0);

    bf16x4 pk[4][2];
#pragma unroll
    for (int kt = 0; kt < 4; kt++)
#pragma unroll
      for (int qt = 0; qt < 2; qt++) {
        int blk = kt - qt + 1;
        float p0 = EXP2(sacc[kt][qt][0] + bbl[blk][0]);
        float p1 = EXP2(sacc[kt][qt][1] + bbl[blk][1]);
        float p2 = EXP2(sacc[kt][qt][2] + bbl[blk][2]);
        float p3 = EXP2(sacc[kt][qt][3] + bbl[blk][3]);
        unsigned int uu[2] = { pk_bf16(p0, p1), pk_bf16(p2, p3) };
        bf16x4 pv; __builtin_memcpy(&pv, uu, 8);
        pk[kt][qt] = pv;
      }

#pragma unroll
    for (int kt = 0; kt < 4; kt++) {
      bf16x4 va[4];
#pragma unroll
      for (int dt = 0; dt < 4; dt++)
        va[dt] = *(const bf16x4*)&KV[2 + g][(dt * 16 + lr) * 72 + kt * 16 + lq * 4];
#pragma unroll
      for (int qt = 0; qt < 2; qt++) {
#pragma unroll
        for (int dt = 0; dt < 4; dt++)
          accO[dt][qt] = __builtin_amdgcn_mfma_f32_16x16x16bf16_1k(va[dt], pk[kt][qt], accO[dt][qt], 0, 0, 0);
        accL[qt] = __builtin_amdgcn_mfma_f32_16x16x16bf16_1k(ones4, pk[kt][qt], accL[qt], 0, 0, 0);
      }
    }

    __syncthreads();
    if (more) {
      *(uint4*)&KV[0][rs * 72 + fs] = kpa;
      *(uint4*)&KV[1][rs * 72 + fs] = kpb;
      *(uint4*)&KV[2][rs * 72 + fs] = vpa;
      *(uint4*)&KV[3][rs * 72 + fs] = vpb;
    }
  }

  float* mrg = (float*)&KV[0][0];
  int slot = (wg * 64 + l) * 34;
  if (g == 1) {
    float2* mp = (float2*)&mrg[slot];
    int j = 0;
#pragma unroll
    for (int dt = 0; dt < 4; dt++)
#pragma unroll
      for (int qt = 0; qt < 2; qt++) {
        mp[j++] = (float2){accO[dt][qt][0], accO[dt][qt][1]};
        mp[j++] = (float2){accO[dt][qt][2], accO[dt][qt][3]};
      }
    mp[16] = (float2){accL[0][0], accL[1][0]};
  }
  __syncthreads();
  if (g == 0) {
    const float2* mp = (const float2*)&mrg[slot];
    int j = 0;
#pragma unroll
    for (int dt = 0; dt < 4; dt++)
#pragma unroll
      for (int qt = 0; qt < 2; qt++) {
        float2 a = mp[j++], b2 = mp[j++];
        accO[dt][qt][0] += a.x;  accO[dt][qt][1] += a.y;
        accO[dt][qt][2] += b2.x; accO[dt][qt][3] += b2.y;
      }
    float2 ls = mp[16];
    float rl0 = 1.0f / (accL[0][0] + ls.x);
    float rl1 = 1.0f / (accL[1][0] + ls.y);
#pragma unroll
    for (int qt = 0; qt < 2; qt++) {
      float rl = qt ? rl1 : rl0;
      int q = q0 + qw + qt * 16 + lr;
#pragma unroll
      for (int dt = 0; dt < 4; dt++) {
        unsigned int s0 = ((unsigned int)f2bf(accO[dt][qt][1] * rl) << 16) | f2bf(accO[dt][qt][0] * rl);
        unsigned int s1 = ((unsigned int)f2bf(accO[dt][qt][3] * rl) << 16) | f2bf(accO[dt][qt][2] * rl);
        *(uint2*)&O[((long)(b_ * SEQ + q)) * 1024 + h * 64 + dt * 16 + lq * 4] = (uint2){s0, s1};
      }
    }
  }
}

extern "C" void kernel_launch(void* const* d_in, const int* in_sizes, int n_in,
                              void* d_out, int out_size, void* d_ws, size_t ws_size,
                              hipStream_t stream) {
  const float* X   = (const float*)d_in[0];
  const float* Wq  = (const float*)d_in[1];
  const float* Wk  = (const float*)d_in[2];
  const float* Wv  = (const float*)d_in[3];
  const float* Wo  = (const float*)d_in[4];
  const float* tbl = (const float*)d_in[5];

  unsigned short* wt    = (unsigned short*)d_ws;       // 4 x 1M elems (Wq,Wk,Wv,Wo transposed)
  unsigned short* xbf   = wt + 4 * 1048576;            // 4M elems
  unsigned short* q_ws  = xbf + 4194304;               // Q,K,V slots (V slot unused)
  unsigned short* k_ws  = q_ws + 4194304;
  unsigned short* v_ws  = k_ws + 4194304;
  unsigned short* vt_ws = v_ws + 4194304;              // V^T (B,H,64,S), written by gemm z=2
  unsigned short* o_ws  = vt_ws + 4194304;
  float* biasF = (float*)(o_ws + 4194304);             // 16 x 4096 fp32 (log2e-scaled)

  prep_kernel<<<3073, 256, 0, stream>>>(X, Wq, Wk, Wv, Wo, tbl, xbf, wt, biasF);
  gemm_kernel<<<dim3(32, 8, 3), 256, 0, stream>>>(xbf, wt, q_ws, vt_ws, nullptr, 0);
  attn_kernel<<<dim3(16, 32), 512, 0, stream>>>(q_ws, k_ws, vt_ws, biasF, o_ws);
  gemm_kernel<<<dim3(32, 8, 1), 256, 0, stream>>>(o_ws, wt + 3 * 1048576, nullptr, nullptr, (float*)d_out, 1);
}

// Round 9
// 212.380 us; speedup vs baseline: 1.0411x; 1.0411x over previous
//
#include <hip/hip_runtime.h>
#include <hip/hip_bf16.h>
#include <math.h>

#define NUM_HEADS 16
#define D_KV 64
#define D_MODEL 1024
#define SEQ 2048
#define BATCH 2
#define LOG2E 1.4426950408889634f

using bf16x8 = __attribute__((ext_vector_type(8))) short;
using bf16x4 = __attribute__((ext_vector_type(4))) short;
using f32x4  = __attribute__((ext_vector_type(4))) float;

__device__ inline unsigned short f2bf(float f) {
  union { float f; unsigned int i; } v; v.f = f;
  unsigned int u = v.i;
  return (unsigned short)((u + 0x7FFFu + ((u >> 16) & 1u)) >> 16);
}
__device__ inline unsigned short f2bf_fast(float f) {
  union { float f; unsigned int i; } v; v.f = f;
  return (unsigned short)((v.i + 0x8000u) >> 16);
}

#if __has_builtin(__builtin_amdgcn_exp2f)
#define EXP2(x) __builtin_amdgcn_exp2f(x)
#else
#define EXP2(x) __expf((x) * 0.6931471805599453f)
#endif

__device__ inline unsigned int pk_bf16(float a, float b) {
#if __has_builtin(__builtin_amdgcn_cvt_pk_bf16_f32)
  auto v = __builtin_amdgcn_cvt_pk_bf16_f32(a, b);
  unsigned int u; __builtin_memcpy(&u, &v, 4);
  return u;
#else
  return ((unsigned int)f2bf_fast(b) << 16) | f2bf_fast(a);
#endif
}

// async global->LDS, 16 B per lane (dest lane-contiguous)
__device__ inline void gld_lds16(const unsigned short* g, unsigned short* l) {
  __builtin_amdgcn_global_load_lds(
      (const __attribute__((address_space(1))) unsigned int*)g,
      (__attribute__((address_space(3))) unsigned int*)l, 16, 0, 0);
}

// ---------------- fused prep: X convert + 4 weight transposes + bias table ----------------
__global__ __launch_bounds__(256) void prep_kernel(const float* __restrict__ X,
                                                   const float* __restrict__ W0,
                                                   const float* __restrict__ W1,
                                                   const float* __restrict__ W2,
                                                   const float* __restrict__ W3,
                                                   const float* __restrict__ tbl,
                                                   unsigned short* __restrict__ xbf,
                                                   unsigned short* __restrict__ wt,
                                                   float* __restrict__ biasF) {
  __shared__ __align__(16) unsigned short T[64][72];
  int bid = blockIdx.x;
  int t = threadIdx.x;
  if (bid < 2048) {
    int i = (bid * 256 + t) * 8;
    __align__(16) unsigned short tmp[8];
#pragma unroll
    for (int e = 0; e < 8; e++) tmp[e] = f2bf(X[i + e]);
    *(uint4*)&xbf[i] = *(uint4*)tmp;
  } else if (bid < 3072) {
    int rem = bid - 2048;
    int z = rem >> 8, tid = rem & 255;
    const float* in = (z == 0) ? W0 : (z == 1) ? W1 : (z == 2) ? W2 : W3;
    unsigned short* o = wt + (long)z * 1048576;
    int r0 = (tid & 15) * 64, c0 = (tid >> 4) * 64;
#pragma unroll
    for (int i = 0; i < 2; i++) {
      int c = t + 256 * i; int r = c >> 3, k8 = (c & 7) * 8;
      const float* src = &in[(long)(r0 + r) * 1024 + c0 + k8];
      __align__(16) unsigned short tmp[8];
#pragma unroll
      for (int e = 0; e < 8; e++) tmp[e] = f2bf(src[e]);
      *(uint4*)&T[r][k8] = *(uint4*)tmp;
    }
    __syncthreads();
#pragma unroll
    for (int i = 0; i < 2; i++) {
      int c = t + 256 * i; int r = c >> 3, k8 = (c & 7) * 8;
      __align__(16) unsigned short tmp[8];
#pragma unroll
      for (int e = 0; e < 8; e++) tmp[e] = T[k8 + e][r];
      *(uint4*)&o[(long)(c0 + r) * 1024 + r0 + k8] = *(uint4*)tmp;
    }
  } else {
#pragma unroll
    for (int ii = 0; ii < 16; ii++) {
      int idx = t + 256 * ii;
      if (idx >= 4095) break;
      int rel = idx - 2047;
      int bucket = (rel > 0) ? 16 : 0;
      int rp = rel < 0 ? -rel : rel;
      int add;
      if (rp < 8) add = rp;
      else {
        int rl = 8 + (int)(logf((float)rp * 0.125f) / logf(16.0f) * 8.0f);
        add = rl < 15 ? rl : 15;
      }
      bucket += add;
#pragma unroll
      for (int h = 0; h < 16; h++) biasF[h * 4096 + idx] = tbl[bucket * 16 + h] * LOG2E;
    }
  }
}

// ---------------- QKV GEMM: C = X(4096x1024) @ Wt(NxK)^T per z ----------------
// z=0 (Q, log2e-scaled) / z=1 (K): bf16 (B,H,S,D); z=2 (V): bf16 transposed (B,H,D,S).
__global__ __launch_bounds__(256) void gemm_kernel(const unsigned short* __restrict__ X,
                                                   const unsigned short* __restrict__ Wt,
                                                   unsigned short* __restrict__ out_b,
                                                   unsigned short* __restrict__ out_vt) {
  __shared__ __align__(16) unsigned short SMEM[128 * 136];   // loop: As|Bs; epilogue: C-tile
  unsigned short* As = SMEM;
  unsigned short* Bs = SMEM + 128 * 32;
  const int K = 1024;
  int m0 = blockIdx.x * 128;
  int n0 = blockIdx.y * 128;
  const unsigned short* W = Wt + (long)blockIdx.z * 1048576;
  unsigned short* outq = out_b + (long)blockIdx.z * 4194304;
  float scale = (blockIdx.z == 0) ? LOG2E : 1.0f;
  int t = threadIdx.x;
  int w = t >> 6, l = t & 63;
  int wr = (w >> 1) * 64, wc = (w & 1) * 64;
  int lr = l & 15, lq = l >> 4;
  f32x4 acc[4][4];
#pragma unroll
  for (int i = 0; i < 4; i++)
#pragma unroll
    for (int j = 0; j < 4; j++) acc[i][j] = (f32x4){0.f, 0.f, 0.f, 0.f};

  for (int k0 = 0; k0 < K; k0 += 32) {
#pragma unroll
    for (int i = 0; i < 2; i++) {
      int c = t + 256 * i;
      int r = c >> 2, kc = (c & 3) * 8;
      gld_lds16(&X[(long)(m0 + r) * K + k0 + kc], &As[c * 8]);
      gld_lds16(&W[(long)(n0 + r) * K + k0 + kc], &Bs[c * 8]);
    }
    __syncthreads();
    bf16x8 a[4], b[4];
#pragma unroll
    for (int mi = 0; mi < 4; mi++) a[mi] = *(const bf16x8*)&As[(wr + mi * 16 + lr) * 32 + lq * 8];
#pragma unroll
    for (int ni = 0; ni < 4; ni++) b[ni] = *(const bf16x8*)&Bs[(wc + ni * 16 + lr) * 32 + lq * 8];
#pragma unroll
    for (int mi = 0; mi < 4; mi++)
#pragma unroll
      for (int ni = 0; ni < 4; ni++)
        acc[mi][ni] = __builtin_amdgcn_mfma_f32_16x16x32_bf16(a[mi], b[ni], acc[mi][ni], 0, 0, 0);
    __syncthreads();
  }

  if (blockIdx.z == 2) {
    unsigned short* Cs = SMEM;
#pragma unroll
    for (int mi = 0; mi < 4; mi++)
#pragma unroll
      for (int ni = 0; ni < 4; ni++) {
        int nl = wc + ni * 16 + lr;
        int ml = wr + mi * 16 + lq * 4;
        unsigned int s0 = pk_bf16(acc[mi][ni][0], acc[mi][ni][1]);
        unsigned int s1 = pk_bf16(acc[mi][ni][2], acc[mi][ni][3]);
        *(uint2*)&Cs[nl * 136 + ml] = (uint2){s0, s1};
      }
    __syncthreads();
    int b2 = m0 >> 11, sbase = m0 & 2047;
#pragma unroll
    for (int i = 0; i < 8; i++) {
      int c = t + 256 * i;
      int row = c >> 4, ch = c & 15;
      uint4 v = *(const uint4*)&Cs[row * 136 + ch * 8];
      int n = n0 + row, h = n >> 6, d = n & 63;
      *(uint4*)&out_vt[(((long)(b2 * 16 + h) * 64 + d) << 11) + sbase + ch * 8] = v;
    }
  } else {
    unsigned short* Cs = SMEM;
#pragma unroll
    for (int mi = 0; mi < 4; mi++)
#pragma unroll
      for (int ni = 0; ni < 4; ni++)
#pragma unroll
        for (int r = 0; r < 4; r++)
          Cs[(wr + mi * 16 + lq * 4 + r) * 136 + wc + ni * 16 + lr] = f2bf(acc[mi][ni][r] * scale);
    __syncthreads();
    int b2 = m0 >> 11, sbase = m0 & 2047;
#pragma unroll
    for (int i = 0; i < 8; i++) {
      int c = t + 256 * i;
      int row = c >> 4, ch = c & 15;
      uint4 v = *(const uint4*)&Cs[row * 136 + ch * 8];
      int n = n0 + ch * 8, h = n >> 6, d = n & 63;
      *(uint4*)&outq[((long)(b2 * 16 + h) * 2048 + sbase + row) * 64 + d] = v;
    }
  }
}

// ---------------- out-projection GEMM: 64x64 tiles, BK=64, 1024 blocks (4/CU) ----------------
__global__ __launch_bounds__(256) void ogemm_kernel(const unsigned short* __restrict__ X,
                                                    const unsigned short* __restrict__ W,
                                                    float* __restrict__ out) {
  __shared__ __align__(16) unsigned char SMEM[64 * 68 * 4];  // staging 16 KB / epilogue fp32
  unsigned short* As = (unsigned short*)SMEM;      // [2 panels][64 rows][32 k]
  unsigned short* Bs = As + 4096;
  float* Csf = (float*)SMEM;
  const int K = 1024;
  int m0 = blockIdx.x * 64;
  int n0 = blockIdx.y * 64;
  int t = threadIdx.x;
  int w = t >> 6, l = t & 63;
  int wr = (w >> 1) * 32, wc = (w & 1) * 32;
  int lr = l & 15, lq = l >> 4;
  f32x4 acc[2][2];
#pragma unroll
  for (int i = 0; i < 2; i++)
#pragma unroll
    for (int j = 0; j < 2; j++) acc[i][j] = (f32x4){0.f, 0.f, 0.f, 0.f};

  for (int k0 = 0; k0 < K; k0 += 64) {
#pragma unroll
    for (int i = 0; i < 2; i++) {
      int c = t + 256 * i;               // dest linear c*8 == p*2048 + r*32 + kc
      int p = c >> 8, r = (c >> 2) & 63, kc = (c & 3) * 8;
      gld_lds16(&X[(long)(m0 + r) * K + k0 + p * 32 + kc], &As[c * 8]);
      gld_lds16(&W[(long)(n0 + r) * K + k0 + p * 32 + kc], &Bs[c * 8]);
    }
    __syncthreads();
    bf16x8 a[2][2], b[2][2];
#pragma unroll
    for (int ks = 0; ks < 2; ks++) {
#pragma unroll
      for (int mi = 0; mi < 2; mi++) a[mi][ks] = *(const bf16x8*)&As[ks * 2048 + (wr + mi * 16 + lr) * 32 + lq * 8];
#pragma unroll
      for (int ni = 0; ni < 2; ni++) b[ni][ks] = *(const bf16x8*)&Bs[ks * 2048 + (wc + ni * 16 + lr) * 32 + lq * 8];
    }
#pragma unroll
    for (int ks = 0; ks < 2; ks++)
#pragma unroll
      for (int mi = 0; mi < 2; mi++)
#pragma unroll
        for (int ni = 0; ni < 2; ni++)
          acc[mi][ni] = __builtin_amdgcn_mfma_f32_16x16x32_bf16(a[mi][ks], b[ni][ks], acc[mi][ni], 0, 0, 0);
    __syncthreads();
  }

#pragma unroll
  for (int mi = 0; mi < 2; mi++)
#pragma unroll
    for (int ni = 0; ni < 2; ni++)
#pragma unroll
      for (int r = 0; r < 4; r++)
        Csf[(wr + mi * 16 + lq * 4 + r) * 68 + wc + ni * 16 + lr] = acc[mi][ni][r];
  __syncthreads();
#pragma unroll
  for (int i = 0; i < 4; i++) {
    int c = t + 256 * i;
    int row = c >> 4, ch = c & 15;
    float4 v = *(const float4*)&Csf[row * 68 + ch * 4];
    *(float4*)&out[(long)(m0 + row) * 1024 + n0 + ch * 4] = v;
  }
}

// ---------------- flash attention: 512-thread blocks, intra-block K-split ----------------
// PV at full rate (16x16x32) via per-wave LDS P scratch, processed in TWO k-halves:
// each half writes a 32(q) x 32(k) P sub-tile (stride 40, exactly 1280 shorts/wave) then
// issues its MFMAs. R8 bug was a single-shot 64-wide write into the 40-stride scratch.
// Same-wave DS ops execute in order -> no barrier needed between halves (WAR safe).
// Row sums in fp32 VALU + 2 epilogue shuffles. No min-wave bound (R4: 128-VGPR cap spills).
__global__ __launch_bounds__(512) void attn_kernel(const unsigned short* __restrict__ Q,
                                                   const unsigned short* __restrict__ Km,
                                                   const unsigned short* __restrict__ Vt,
                                                   const float* __restrict__ biasF,
                                                   unsigned short* __restrict__ O) {
  __shared__ __align__(16) unsigned short KV[4][4608];  // [0,1]=K par0/1, [2,3]=V par0/1 (64x72)
  __shared__ __align__(16) float biasRf[2][2176];
  __shared__ __align__(16) unsigned short Ps[8 * 1280]; // per-wave P scratch: 32 rows x 40 (one k-half)
  int q0 = blockIdx.x * 128;
  int bh = blockIdx.y;
  int b_ = bh >> 4, h = bh & 15;
  const unsigned short* Qb = Q  + (long)bh * SEQ * 64;
  const unsigned short* Kb = Km + (long)bh * SEQ * 64;
  const unsigned short* Vb = Vt + (long)bh * 64 * SEQ;
  const float* btabF = biasF + h * 4096;
  int t = threadIdx.x;
  int w = t >> 6, l = t & 63;
  int g = w >> 2, wg = w & 3;
  int lr = l & 15, lq = l >> 4;
  int qw = wg * 32;

  // 2 shift-replicated fp32 bias copies (even-aligned float2 reads later)
  int gbase = 1920 - q0;
  for (int i = t; i < 2176; i += 512) {
    int g0 = gbase + i;     if (g0 > 4094) g0 = 4094;
    int g1 = gbase + i + 1; if (g1 > 4094) g1 = 4094;
    biasRf[0][i] = btabF[g0];
    biasRf[1][i] = btabF[g1];
  }

  bf16x8 aq[2][2];
#pragma unroll
  for (int qt = 0; qt < 2; qt++)
#pragma unroll
    for (int ks = 0; ks < 2; ks++)
      aq[qt][ks] = *(const bf16x8*)&Qb[(long)(q0 + qw + qt * 16 + lr) * 64 + ks * 32 + lq * 8];

  int rs = t >> 3, fs = (t & 7) * 8;

  uint4 kpa = *(const uint4*)&Kb[(long)rs * 64 + fs];
  uint4 kpb = *(const uint4*)&Kb[(long)(64 + rs) * 64 + fs];
  uint4 vpa = *(const uint4*)&Vb[(long)rs * SEQ + fs];
  uint4 vpb = *(const uint4*)&Vb[(long)rs * SEQ + 64 + fs];
  *(uint4*)&KV[0][rs * 72 + fs] = kpa;
  *(uint4*)&KV[1][rs * 72 + fs] = kpb;
  *(uint4*)&KV[2][rs * 72 + fs] = vpa;
  *(uint4*)&KV[3][rs * 72 + fs] = vpb;

  f32x4 accO[4][2];   // [dt][qt], O^T C-tiles (row=d, col=q)
  float rsum[2] = {0.f, 0.f};
#pragma unroll
  for (int qt = 0; qt < 2; qt++)
#pragma unroll
    for (int dt = 0; dt < 4; dt++) accO[dt][qt] = (f32x4){0.f, 0.f, 0.f, 0.f};

  // bias index: global idx = vb + k0 + kt*16 - qt*16 + r
  int vb = 127 + lq * 4 - qw - lr;
  int bj2 = vb & 1;
  const float* brow = biasRf[bj2];
  int pbc = vb - bj2 - 16;
  unsigned short* Pw = Ps + w * 1280;

  for (int i = 0; i < 16; i++) {
    __syncthreads();
    int k0 = (2 * i + g) * 64;
    bool more = i < 15;

    // ---- bias blocks (5 x 2 float2, aligned) ----
    float2 bbl[5][2];
    int pb = pbc + k0;
#pragma unroll
    for (int m = 0; m < 5; m++) {
      bbl[m][0] = *(const float2*)&brow[pb + 16 * m];
      bbl[m][1] = *(const float2*)&brow[pb + 16 * m + 2];
    }

    bf16x8 bk[4][2];
#pragma unroll
    for (int kt = 0; kt < 4; kt++)
#pragma unroll
      for (int ks = 0; ks < 2; ks++)
        bk[kt][ks] = *(const bf16x8*)&KV[g][(kt * 16 + lr) * 72 + ks * 32 + lq * 8];

    if (more) {
      const unsigned short* Kn = Kb + (long)(2 * i + 2) * 64 * 64;
      const unsigned short* Vn = Vb + (2 * i + 2) * 64;
      kpa = *(const uint4*)&Kn[(long)rs * 64 + fs];
      kpb = *(const uint4*)&Kn[(long)(64 + rs) * 64 + fs];
      vpa = *(const uint4*)&Vn[(long)rs * SEQ + fs];
      vpb = *(const uint4*)&Vn[(long)rs * SEQ + 64 + fs];
    }

    // ---- S^T = K Q^T ----
    f32x4 sacc[4][2];
#pragma unroll
    for (int kt = 0; kt < 4; kt++)
#pragma unroll
      for (int qt = 0; qt < 2; qt++) sacc[kt][qt] = (f32x4){0.f, 0.f, 0.f, 0.f};
#pragma unroll
    for (int ks = 0; ks < 2; ks++)
#pragma unroll
      for (int kt = 0; kt < 4; kt++)
#pragma unroll
        for (int qt = 0; qt < 2; qt++)
          sacc[kt][qt] = __builtin_amdgcn_mfma_f32_16x16x32_bf16(bk[kt][ks], aq[qt][ks], sacc[kt][qt], 0, 0, 0);

    // ---- softmax + PV in two k-halves (scratch holds one 32x32 half at a time) ----
#pragma unroll
    for (int ktp = 0; ktp < 2; ktp++) {
#pragma unroll
      for (int kth = 0; kth < 2; kth++) {
        int kt = ktp * 2 + kth;
#pragma unroll
        for (int qt = 0; qt < 2; qt++) {
          int blk = kt - qt + 1;
          float p0 = EXP2(sacc[kt][qt][0] + bbl[blk][0].x);
          float p1 = EXP2(sacc[kt][qt][1] + bbl[blk][0].y);
          float p2 = EXP2(sacc[kt][qt][2] + bbl[blk][1].x);
          float p3 = EXP2(sacc[kt][qt][3] + bbl[blk][1].y);
          rsum[qt] += (p0 + p1) + (p2 + p3);
          *(uint2*)&Pw[(qt * 16 + lr) * 40 + kth * 16 + lq * 4] =
              (uint2){ pk_bf16(p0, p1), pk_bf16(p2, p3) };
        }
      }
      // O^T += V^T P (this k-half), K=32 full-rate MFMA
      bf16x8 va8[4];
#pragma unroll
      for (int dt = 0; dt < 4; dt++)
        va8[dt] = *(const bf16x8*)&KV[2 + g][(dt * 16 + lr) * 72 + ktp * 32 + lq * 8];
      bf16x8 pb8[2];
#pragma unroll
      for (int qt = 0; qt < 2; qt++)
        pb8[qt] = *(const bf16x8*)&Pw[(qt * 16 + lr) * 40 + lq * 8];
#pragma unroll
      for (int qt = 0; qt < 2; qt++)
#pragma unroll
        for (int dt = 0; dt < 4; dt++)
          accO[dt][qt] = __builtin_amdgcn_mfma_f32_16x16x32_bf16(va8[dt], pb8[qt], accO[dt][qt], 0, 0, 0);
    }

    __syncthreads();
    if (more) {
      *(uint4*)&KV[0][rs * 72 + fs] = kpa;
      *(uint4*)&KV[1][rs * 72 + fs] = kpb;
      *(uint4*)&KV[2][rs * 72 + fs] = vpa;
      *(uint4*)&KV[3][rs * 72 + fs] = vpb;
    }
  }

  // reduce row sums across lq quads (lanes share q = l&15)
#pragma unroll
  for (int qt = 0; qt < 2; qt++) {
    rsum[qt] += __shfl_xor(rsum[qt], 16);
    rsum[qt] += __shfl_xor(rsum[qt], 32);
  }

  // ---- merge group partials via LDS overlay on KV ----
  float* mrg = (float*)&KV[0][0];
  int slot = (wg * 64 + l) * 34;
  if (g == 1) {
    float2* mp = (float2*)&mrg[slot];
    int j = 0;
#pragma unroll
    for (int dt = 0; dt < 4; dt++)
#pragma unroll
      for (int qt = 0; qt < 2; qt++) {
        mp[j++] = (float2){accO[dt][qt][0], accO[dt][qt][1]};
        mp[j++] = (float2){accO[dt][qt][2], accO[dt][qt][3]};
      }
    mp[16] = (float2){rsum[0], rsum[1]};
  }
  __syncthreads();
  if (g == 0) {
    const float2* mp = (const float2*)&mrg[slot];
    int j = 0;
#pragma unroll
    for (int dt = 0; dt < 4; dt++)
#pragma unroll
      for (int qt = 0; qt < 2; qt++) {
        float2 a = mp[j++], b2 = mp[j++];
        accO[dt][qt][0] += a.x;  accO[dt][qt][1] += a.y;
        accO[dt][qt][2] += b2.x; accO[dt][qt][3] += b2.y;
      }
    float2 ls = mp[16];
    float rl0 = 1.0f / (rsum[0] + ls.x);
    float rl1 = 1.0f / (rsum[1] + ls.y);
#pragma unroll
    for (int qt = 0; qt < 2; qt++) {
      float rl = qt ? rl1 : rl0;
      int q = q0 + qw + qt * 16 + lr;
#pragma unroll
      for (int dt = 0; dt < 4; dt++) {
        unsigned int s0 = ((unsigned int)f2bf(accO[dt][qt][1] * rl) << 16) | f2bf(accO[dt][qt][0] * rl);
        unsigned int s1 = ((unsigned int)f2bf(accO[dt][qt][3] * rl) << 16) | f2bf(accO[dt][qt][2] * rl);
        *(uint2*)&O[((long)(b_ * SEQ + q)) * 1024 + h * 64 + dt * 16 + lq * 4] = (uint2){s0, s1};
      }
    }
  }
}

extern "C" void kernel_launch(void* const* d_in, const int* in_sizes, int n_in,
                              void* d_out, int out_size, void* d_ws, size_t ws_size,
                              hipStream_t stream) {
  const float* X   = (const float*)d_in[0];
  const float* Wq  = (const float*)d_in[1];
  const float* Wk  = (const float*)d_in[2];
  const float* Wv  = (const float*)d_in[3];
  const float* Wo  = (const float*)d_in[4];
  const float* tbl = (const float*)d_in[5];

  // compact workspace (40.25 MB): o_ws aliases xbf (dead after QKV gemm)
  unsigned short* wt    = (unsigned short*)d_ws;       // 4 x 1M elems
  unsigned short* xbf   = wt + 4 * 1048576;            // X bf16; later reused as attn O
  unsigned short* q_ws  = xbf + 4194304;
  unsigned short* k_ws  = q_ws + 4194304;
  unsigned short* vt_ws = k_ws + 4194304;              // V^T (B,H,64,S), written by gemm z=2
  float* biasF = (float*)(vt_ws + 4194304);            // 16 x 4096 fp32 (log2e-scaled)
  unsigned short* o_ws  = xbf;

  prep_kernel<<<3073, 256, 0, stream>>>(X, Wq, Wk, Wv, Wo, tbl, xbf, wt, biasF);
  gemm_kernel<<<dim3(32, 8, 3), 256, 0, stream>>>(xbf, wt, q_ws, vt_ws);
  attn_kernel<<<dim3(16, 32), 512, 0, stream>>>(q_ws, k_ws, vt_ws, biasF, o_ws);
  ogemm_kernel<<<dim3(64, 16), 256, 0, stream>>>(o_ws, wt + 3 * 1048576, (float*)d_out);
}